// Round 6
// baseline (179.829 us; speedup 1.0000x reference)
//
#include <hip/hip_runtime.h>
#include <hip/hip_bf16.h>

// ZoomAttention: x[2,2048,1024] -> qkv proj -> 16-head attn with -gamma*dist bias -> proj
// GEMMs: C = A * B^T with bf16 MFMA 16x16x32. Attention: 32x32x16 swapped-QK flash,
// 2 KV-groups per block (8 waves), no-max softmax (scores provably bounded).

typedef __attribute__((ext_vector_type(8))) short bf16x8;
typedef __attribute__((ext_vector_type(4))) float f32x4;
typedef __attribute__((ext_vector_type(16))) float f32x16;
typedef __attribute__((ext_vector_type(4))) unsigned short us4;
typedef __attribute__((ext_vector_type(2))) unsigned int u32x2;
typedef __attribute__((ext_vector_type(4))) _Float16 f16x4;
typedef __attribute__((ext_vector_type(8))) _Float16 f16x8;

#define MFMA(a, b, c) __builtin_amdgcn_mfma_f32_16x16x32_bf16((a), (b), (c), 0, 0, 0)
#define MFMA32(a, b, c) __builtin_amdgcn_mfma_f32_32x32x16_bf16((a), (b), (c), 0, 0, 0)

__device__ __forceinline__ unsigned short f2bf(float f) {
  unsigned u = __float_as_uint(f);
  u += 0x7fffu + ((u >> 16) & 1u);       // round-to-nearest-even
  return (unsigned short)(u >> 16);
}

__device__ __forceinline__ unsigned cvtpk_bf16(float lo, float hi) {
  unsigned r;
  asm("v_cvt_pk_bf16_f32 %0, %1, %2" : "=v"(r) : "v"(lo), "v"(hi));
  return r;  // lo in bits[15:0], hi in bits[31:16]
}

// swap upper 32 lanes of a with lower 32 lanes of b
#define PLSWAP(a, b) asm volatile("v_permlane32_swap_b32 %0, %1" : "+v"(a), "+v"(b))

__device__ __forceinline__ float tree16(const float* p) {
  float t0 = (p[0] + p[1]) + (p[2] + p[3]);
  float t1 = (p[4] + p[5]) + (p[6] + p[7]);
  float t2 = (p[8] + p[9]) + (p[10] + p[11]);
  float t3 = (p[12] + p[13]) + (p[14] + p[15]);
  return (t0 + t1) + (t2 + t3);
}

// ---------- elementwise f32 -> bf16, 8 elems/thread ----------
__global__ __launch_bounds__(256) void k_conv(const float* __restrict__ in,
                                              short* __restrict__ out, int n8) {
  int i = blockIdx.x * blockDim.x + threadIdx.x;
  if (i >= n8) return;
  float4 a = ((const float4*)in)[2 * i];
  float4 b = ((const float4*)in)[2 * i + 1];
  us4 lo, hi;
  lo.x = f2bf(a.x); lo.y = f2bf(a.y); lo.z = f2bf(a.z); lo.w = f2bf(a.w);
  hi.x = f2bf(b.x); hi.y = f2bf(b.y); hi.z = f2bf(b.z); hi.w = f2bf(b.w);
  us4* o = (us4*)(out + 8 * (size_t)i);
  o[0] = lo; o[1] = hi;
}

// ---------- elementwise f32 -> fp16, 8 elems/thread ----------
__global__ __launch_bounds__(256) void k_convh(const float* __restrict__ in,
                                               _Float16* __restrict__ out, int n8) {
  int i = blockIdx.x * blockDim.x + threadIdx.x;
  if (i >= n8) return;
  float4 a = ((const float4*)in)[2 * i];
  float4 b = ((const float4*)in)[2 * i + 1];
  f16x8 v;
  v[0] = (_Float16)a.x; v[1] = (_Float16)a.y; v[2] = (_Float16)a.z; v[3] = (_Float16)a.w;
  v[4] = (_Float16)b.x; v[5] = (_Float16)b.y; v[6] = (_Float16)b.z; v[7] = (_Float16)b.w;
  *(f16x8*)(out + 8 * (size_t)i) = v;
}

// ---------- tiled transpose + convert: in[R][C] f32 -> out[C][R] bf16 ----------
__global__ void k_transpose(const float* __restrict__ in, short* __restrict__ out,
                            int R, int C) {
  __shared__ float t[32][33];
  int c0 = blockIdx.x * 32, r0 = blockIdx.y * 32;
  int tx = threadIdx.x, ty = threadIdx.y;
#pragma unroll
  for (int j = 0; j < 32; j += 8)
    t[ty + j][tx] = in[(size_t)(r0 + ty + j) * C + c0 + tx];
  __syncthreads();
#pragma unroll
  for (int j = 0; j < 32; j += 8)
    out[(size_t)(c0 + ty + j) * R + r0 + tx] = (short)f2bf(t[tx][ty + j]);
}

// ---------- GEMM C[M][N] = A[M][K] * (B[N][K])^T, bf16 in, f32 acc ----------
// BM=128: 4 waves in 2x2, each 64x64 of the 128x128 tile.
// BM=64 : 4 waves side-by-side, each 64x32 of the 64x128 tile (occupancy variant).
// MODE 0: scatter qkv into Q (pre-scaled by 2^-5*log2e), K, Vt. MODE 1: f32 C.
template <int MODE, int BM>
__global__ __launch_bounds__(256) void k_gemm(const short* __restrict__ A,
                                              const short* __restrict__ B,
                                              const float* __restrict__ bias,
                                              void* __restrict__ C0, void* __restrict__ C1,
                                              void* __restrict__ C2, int M, int N, int K) {
  __shared__ __align__(16) short bufA[2][BM * 32];
  __shared__ __align__(16) short bufB[2][128 * 32];
  const int tid = threadIdx.x, lane = tid & 63, wave = tid >> 6;
  const int m0 = blockIdx.y * BM, n0 = blockIdx.x * 128;
  const int wm = (BM == 128) ? (wave >> 1) * 64 : 0;
  const int wn = (BM == 128) ? (wave & 1) * 64 : wave * 32;
  const int NI = (BM == 128) ? 4 : 2;
  const int KT = K >> 5;
  f32x4 acc[4][4] = {};

  const short* ga = A + (size_t)m0 * K;
  const short* gb = B + (size_t)n0 * K;

#define STAGE(kt, bsel)                                                                   \
  {                                                                                       \
    const short* pa = ga + (kt) * 32;                                                     \
    const short* pb = gb + (kt) * 32;                                                     \
    _Pragma("unroll") for (int i = 0; i < BM / 64; i++) {                                 \
      int s = i * 256 + tid;                                                              \
      __builtin_amdgcn_global_load_lds(                                                   \
          (const __attribute__((address_space(1))) void*)(pa + (size_t)(s >> 2) * K +     \
                                                          (s & 3) * 8),                   \
          (__attribute__((address_space(3))) void*)(&bufA[bsel][(i * 256 + wave * 64) * 8]), \
          16, 0, 0);                                                                      \
    }                                                                                     \
    _Pragma("unroll") for (int i = 0; i < 2; i++) {                                       \
      int s = i * 256 + tid;                                                              \
      __builtin_amdgcn_global_load_lds(                                                   \
          (const __attribute__((address_space(1))) void*)(pb + (size_t)(s >> 2) * K +     \
                                                          (s & 3) * 8),                   \
          (__attribute__((address_space(3))) void*)(&bufB[bsel][(i * 256 + wave * 64) * 8]), \
          16, 0, 0);                                                                      \
    }                                                                                     \
  }

  STAGE(0, 0)
  for (int kt = 0; kt < KT; ++kt) {
    const int cur = kt & 1;
    __syncthreads();
    if (kt + 1 < KT) STAGE(kt + 1, cur ^ 1)
    bf16x8 af[4], bfr[4];
#pragma unroll
    for (int i = 0; i < 4; i++)
      af[i] = *(const bf16x8*)&bufA[cur][(wm + i * 16 + (lane & 15)) * 32 + (lane >> 4) * 8];
#pragma unroll
    for (int i = 0; i < NI; i++)
      bfr[i] = *(const bf16x8*)&bufB[cur][(wn + i * 16 + (lane & 15)) * 32 + (lane >> 4) * 8];
#pragma unroll
    for (int mi = 0; mi < 4; mi++)
#pragma unroll
      for (int ni = 0; ni < NI; ni++) acc[mi][ni] = MFMA(af[mi], bfr[ni], acc[mi][ni]);
  }
#undef STAGE

#pragma unroll
  for (int mi = 0; mi < 4; mi++)
#pragma unroll
    for (int ni = 0; ni < NI; ni++) {
      int row0 = m0 + wm + mi * 16 + (lane >> 4) * 4;
      int col = n0 + wn + ni * 16 + (lane & 15);
      float bv = bias[col];
      if constexpr (MODE == 0) {
        int which = col >> 10, h = (col >> 6) & 15, d = col & 63;
        int b = row0 >> 11, nt0 = row0 & 2047;
        if (which == 2) {
          us4 pk;
          pk.x = f2bf(acc[mi][ni][0] + bv);
          pk.y = f2bf(acc[mi][ni][1] + bv);
          pk.z = f2bf(acc[mi][ni][2] + bv);
          pk.w = f2bf(acc[mi][ni][3] + bv);
          *(us4*)((short*)C2 + ((size_t)((b << 4) + h) * 64 + d) * 2048 + nt0) = pk;
        } else {
          // Q gets pre-scaled by 2^-5 * log2(e) so attn bias is a single FMA
          float sc = (which == 0) ? 0.045084220f : 1.0f;
          short* dst = (which == 0) ? (short*)C0 : (short*)C1;
#pragma unroll
          for (int r = 0; r < 4; r++)
            dst[((size_t)((b << 4) + h) * 2048 + nt0 + r) * 64 + d] =
                (short)f2bf((acc[mi][ni][r] + bv) * sc);
        }
      } else {
        float* o = (float*)C0;
#pragma unroll
        for (int r = 0; r < 4; r++) o[(size_t)(row0 + r) * N + col] = acc[mi][ni][r] + bv;
      }
    }
}

// ---------- fused attention: 32x32x16 swapped-QK, 2 KV-groups, no-max softmax ----------
// Q[bh][n][64] (pre-scaled), K[bh][n][64], Vt[bh][64][n] bf16; dist fp16; out bf16.
// 512 threads = 8 waves; waves 0-3 (group 0) do even 64-KV tiles, 4-7 odd tiles.
// Lane pair (l, l^32) owns q-row qbase+(l&31). Scores bounded (|x|<~5 in log2
// domain) -> softmax without max tracking; group partials merge by plain add.
__global__ __launch_bounds__(512, 4) void k_attn(const short* __restrict__ Qb,
                                                 const short* __restrict__ Kb,
                                                 const short* __restrict__ Vt,
                                                 const float* __restrict__ gamma,
                                                 const _Float16* __restrict__ dh,
                                                 short* __restrict__ attn_out) {
  __shared__ __align__(16) short bufK[2][2][64 * 64];   // [group][dbuf]
  __shared__ __align__(16) short bufV[2][2][64 * 64];
  __shared__ float mls[4][32];
  const int tid = threadIdx.x;
  const int lane = tid & 63, wave = tid >> 6;
  const int grp = wave >> 2, w4 = wave & 3;
  const int q32 = lane & 31, hl = lane >> 5;
  const int w = blockIdx.x;
  const int xcd = w & 7, idx = w >> 3;
  const int bh = (xcd << 2) | (idx >> 4);        // 4 heads per XCD
  const int qblock = idx & 15;                   // 16 q-blocks of 128 rows
  const int qbase = qblock * 128 + w4 * 32;
  const float G2 = gamma[bh] * 1.4426950408889634f;
  const size_t head = (size_t)bh * 2048 * 64;
  const int qrow = qbase + q32;                  // q-row owned by this lane pair
  const _Float16* drow = dh + (size_t)qrow * 2048;
  const char* kptr = (const char*)(Kb + head);   // [2048][64] bf16, 128B rows
  const char* vptr = (const char*)(Vt + head);   // [64][2048] bf16, 4096B rows
  const int swz = (q32 & 7) << 4;

  // Q B-frags (already scaled by 2^-5*log2e): col=q32, k-slice ds*16 + hl*8
  bf16x8 qf[4];
#pragma unroll
  for (int ds = 0; ds < 4; ds++)
    qf[ds] = *(const bf16x8*)&Qb[head + (size_t)qrow * 64 + ds * 16 + hl * 8];

  // Stage this group's 64x64 bf16 K and V tiles (8KB each): 256 group-threads
  // x 2 x 16B. LDS linear; global source pre-applies XOR (byte ^= (row&7)<<4).
#define STAGEKV(kb, bsel)                                                                  \
  {                                                                                        \
    _Pragma("unroll") for (int i = 0; i < 2; i++) {                                        \
      int s = i * 256 + (tid & 255);                                                       \
      int row = s >> 3, sw = ((s & 7) * 16) ^ ((row & 7) << 4);                            \
      __builtin_amdgcn_global_load_lds(                                                    \
          (const __attribute__((address_space(1))) void*)(kptr + (size_t)(kb) * 128 +      \
                                                          row * 128 + sw),                 \
          (__attribute__((address_space(3))) void*)(&bufK[grp][bsel][(i * 256 + w4 * 64) * 8]),\
          16, 0, 0);                                                                       \
      __builtin_amdgcn_global_load_lds(                                                    \
          (const __attribute__((address_space(1))) void*)(vptr + (size_t)row * 4096 +      \
                                                          (size_t)(kb) * 2 + sw),          \
          (__attribute__((address_space(3))) void*)(&bufV[grp][bsel][(i * 256 + w4 * 64) * 8]),\
          16, 0, 0);                                                                       \
    }                                                                                      \
  }

  float ls = 0.f;
  f32x16 acc0 = {}, acc1 = {};

  STAGEKV(grp * 64, 0)

  // dist for this group's first tile: lane's kv slots = t*32 + a*8 + hl*4 + {0..3}
  f16x4 dd0[4], dd1[4];
#pragma unroll
  for (int a = 0; a < 4; a++) {
    dd0[a] = *(const f16x4*)&drow[grp * 64 + a * 8 + hl * 4];
    dd1[a] = *(const f16x4*)&drow[grp * 64 + 32 + a * 8 + hl * 4];
  }

  for (int it = 0; it < 16; ++it) {
    const int cur = it & 1;
    const int kb = (2 * it + grp) * 64;
    __syncthreads();  // staged tiles (both groups) landed; prev LDS reads done
    if (it + 1 < 16) STAGEKV(kb + 128, cur ^ 1)

    // ---- dist prefetch for next own tile, issued EARLY so its latency hides
    // under this iteration's compute (it only has to land by the next barrier).
    const int kbn = (kb + 128) & 2047;
    f16x4 dn0[4], dn1[4];
#pragma unroll
    for (int a = 0; a < 4; a++) {
      dn0[a] = *(const f16x4*)&drow[kbn + a * 8 + hl * 4];
      dn1[a] = *(const f16x4*)&drow[kbn + 32 + a * 8 + hl * 4];
    }

    // ---- QK^T: A = K rows (kv), B = Q ----
    const char* kbase = (const char*)&bufK[grp][cur][0];
    f32x16 s0 = {}, s1 = {};
    __builtin_amdgcn_s_setprio(1);
#pragma unroll
    for (int ds = 0; ds < 4; ds++) {
      int c = (ds * 32 + hl * 16) ^ swz;
      bf16x8 a0 = *(const bf16x8*)(kbase + q32 * 128 + c);
      bf16x8 a1 = *(const bf16x8*)(kbase + (32 + q32) * 128 + c);
      s0 = MFMA32(a0, qf[ds], s0);
      s1 = MFMA32(a1, qf[ds], s1);
    }
    __builtin_amdgcn_s_setprio(0);

    // ---- no-max softmax: p = exp2(s - G2*d); reg 4a+b -> kv = t*32+8a+4hl+b ----
    float p0[16], p1[16];
#pragma unroll
    for (int a = 0; a < 4; a++)
#pragma unroll
      for (int b = 0; b < 4; b++) {
        p0[4 * a + b] = __builtin_amdgcn_exp2f(s0[4 * a + b] - G2 * (float)dd0[a][b]);
        p1[4 * a + b] = __builtin_amdgcn_exp2f(s1[4 * a + b] - G2 * (float)dd1[a][b]);
      }
    ls += tree16(p0) + tree16(p1);

    // ---- P -> bf16 B-frags in-register ----
    unsigned P0[4][2], P1[4][2];
#pragma unroll
    for (int a = 0; a < 4; a++)
#pragma unroll
      for (int wd = 0; wd < 2; wd++) {
        P0[a][wd] = cvtpk_bf16(p0[4 * a + 2 * wd], p0[4 * a + 2 * wd + 1]);
        P1[a][wd] = cvtpk_bf16(p1[4 * a + 2 * wd], p1[4 * a + 2 * wd + 1]);
      }
    PLSWAP(P0[0][0], P0[1][0]); PLSWAP(P0[0][1], P0[1][1]);
    PLSWAP(P0[2][0], P0[3][0]); PLSWAP(P0[2][1], P0[3][1]);
    PLSWAP(P1[0][0], P1[1][0]); PLSWAP(P1[0][1], P1[1][1]);
    PLSWAP(P1[2][0], P1[3][0]); PLSWAP(P1[2][1], P1[3][1]);

    union { unsigned u[4]; bf16x8 v; } pf00, pf01, pf10, pf11;
    pf00.u[0] = P0[0][0]; pf00.u[1] = P0[0][1]; pf00.u[2] = P0[1][0]; pf00.u[3] = P0[1][1];
    pf01.u[0] = P0[2][0]; pf01.u[1] = P0[2][1]; pf01.u[2] = P0[3][0]; pf01.u[3] = P0[3][1];
    pf10.u[0] = P1[0][0]; pf10.u[1] = P1[0][1]; pf10.u[2] = P1[1][0]; pf10.u[3] = P1[1][1];
    pf11.u[0] = P1[2][0]; pf11.u[1] = P1[2][1]; pf11.u[2] = P1[3][0]; pf11.u[3] = P1[3][1];

    // ---- PV: A = Vt rows (dv), B = P ----
    const char* vbase = (const char*)&bufV[grp][cur][0];
    __builtin_amdgcn_s_setprio(1);
#pragma unroll
    for (int dt = 0; dt < 2; dt++) {
      f32x16* ac = dt ? &acc1 : &acc0;
      int vr = (dt * 32 + q32) * 128;
      bf16x8 v00 = *(const bf16x8*)(vbase + vr + ((0 * 64 + 0 * 32 + hl * 16) ^ swz));
      bf16x8 v01 = *(const bf16x8*)(vbase + vr + ((0 * 64 + 1 * 32 + hl * 16) ^ swz));
      bf16x8 v10 = *(const bf16x8*)(vbase + vr + ((1 * 64 + 0 * 32 + hl * 16) ^ swz));
      bf16x8 v11 = *(const bf16x8*)(vbase + vr + ((1 * 64 + 1 * 32 + hl * 16) ^ swz));
      *ac = MFMA32(v00, pf00.v, *ac);
      *ac = MFMA32(v01, pf01.v, *ac);
      *ac = MFMA32(v10, pf10.v, *ac);
      *ac = MFMA32(v11, pf11.v, *ac);
    }
    __builtin_amdgcn_s_setprio(0);

#pragma unroll
    for (int a = 0; a < 4; a++) { dd0[a] = dn0[a]; dd1[a] = dn1[a]; }
  }
#undef STAGEKV

  // ---- merge group partials (plain add: same softmax scale, no max) ----
  __syncthreads();
  float* mrg = (float*)&bufK[0][0][0];  // [4][32][64] f32, 16B-chunk XOR by q32&15
  if (grp == 1) {
    float lsr = ls + __shfl_xor(ls, 32, 64);
    if (hl == 0) mls[w4][q32] = lsr;
#pragma unroll
    for (int dt = 0; dt < 2; dt++) {
      const f32x16* ac = dt ? &acc1 : &acc0;
#pragma unroll
      for (int a = 0; a < 4; a++) {
        int chunk = (dt * 8 + a * 2 + hl) ^ (q32 & 15);
        f32x4 v;
        v.x = (*ac)[4 * a + 0]; v.y = (*ac)[4 * a + 1];
        v.z = (*ac)[4 * a + 2]; v.w = (*ac)[4 * a + 3];
        *(f32x4*)((char*)mrg + (w4 * 32 + q32) * 256 + chunk * 16) = v;
      }
    }
  }
  __syncthreads();
  if (grp == 0) {
    const int b_ = bh >> 4, h_ = bh & 15;
    float lsr = ls + __shfl_xor(ls, 32, 64);
    float linv = 1.0f / (lsr + mls[w4][q32]);
    size_t base = ((size_t)b_ * 2048 + qrow) * 1024 + h_ * 64;
#pragma unroll
    for (int dt = 0; dt < 2; dt++) {
      const f32x16* ac = dt ? &acc1 : &acc0;
#pragma unroll
      for (int a = 0; a < 4; a++) {
        int chunk = (dt * 8 + a * 2 + hl) ^ (q32 & 15);
        f32x4 vB = *(const f32x4*)((const char*)mrg + (w4 * 32 + q32) * 256 + chunk * 16);
        u32x2 wv;
        wv.x = cvtpk_bf16(((*ac)[4 * a + 0] + vB.x) * linv, ((*ac)[4 * a + 1] + vB.y) * linv);
        wv.y = cvtpk_bf16(((*ac)[4 * a + 2] + vB.z) * linv, ((*ac)[4 * a + 3] + vB.w) * linv);
        *(u32x2*)&attn_out[base + dt * 32 + a * 8 + hl * 4] = wv;
      }
    }
  }
}

extern "C" void kernel_launch(void* const* d_in, const int* in_sizes, int n_in,
                              void* d_out, int out_size, void* d_ws, size_t ws_size,
                              hipStream_t stream) {
  const float* x = (const float*)d_in[0];       // [2,2048,1024]
  const float* gamma = (const float*)d_in[1];   // [2,16]
  const float* dist = (const float*)d_in[2];    // [2048,2048]
  const float* qkv_w = (const float*)d_in[3];   // [1024,3072]
  const float* qkv_b = (const float*)d_in[4];   // [3072]
  const float* proj_w = (const float*)d_in[5];  // [1024,1024]
  const float* proj_b = (const float*)d_in[6];  // [1024]
  float* out = (float*)d_out;                   // [4096,1024]

  const size_t MB = 1024 * 1024;
  char* ws = (char*)d_ws;
  short* xb = (short*)(ws + 0 * MB);     // 8MB  x bf16 [4096][1024]
  short* wT = (short*)(ws + 8 * MB);     // 6MB  qkv_w^T bf16 [3072][1024]
  short* pT = (short*)(ws + 14 * MB);    // 2MB  proj_w^T bf16 [1024][1024]
  short* Qb = (short*)(ws + 16 * MB);    // 8MB  [32][2048][64] (pre-scaled)
  short* Kb = (short*)(ws + 24 * MB);    // 8MB
  short* Vt = (short*)(ws + 32 * MB);    // 8MB  [32][64][2048]
  _Float16* dhh = (_Float16*)(ws + 40 * MB);  // 8MB dist fp16 [2048][2048]
  short* attn = (short*)(ws + 0 * MB);   // reuse xb region: [4096][1024] bf16

  // x -> bf16; dist -> fp16
  k_conv<<<dim3((4096 * 1024 / 8 + 255) / 256), dim3(256), 0, stream>>>(x, xb, 4096 * 1024 / 8);
  k_convh<<<dim3(2048), dim3(256), 0, stream>>>(dist, dhh, 2048 * 2048 / 8);
  // weight transposes
  k_transpose<<<dim3(96, 32), dim3(32, 8), 0, stream>>>(qkv_w, wT, 1024, 3072);
  k_transpose<<<dim3(32, 32), dim3(32, 8), 0, stream>>>(proj_w, pT, 1024, 1024);
  // qkv projection + scatter
  k_gemm<0, 128><<<dim3(24, 32), dim3(256), 0, stream>>>(xb, wT, qkv_b, Qb, Kb, Vt,
                                                         4096, 3072, 1024);
  // attention
  k_attn<<<dim3(512), dim3(512), 0, stream>>>(Qb, Kb, Vt, gamma, dhh, attn);
  // output projection (64-row tiles: 512 blocks -> 2 blocks/CU)
  k_gemm<1, 64><<<dim3(8, 64), dim3(256), 0, stream>>>(attn, pT, proj_b, out, nullptr, nullptr,
                                                       4096, 1024, 1024);
}

// Round 7
// 147.806 us; speedup vs baseline: 1.2167x; 1.2167x over previous
//
#include <hip/hip_runtime.h>
#include <hip/hip_bf16.h>

// ZoomAttention: x[2,2048,1024] -> qkv proj -> 16-head attn with -gamma*dist bias -> proj
// GEMMs: C = A * B^T with bf16 MFMA 16x16x32. Attention: 32x32x16 swapped-QK flash,
// 2 KV-groups per block (8 waves), no-max softmax (scores provably bounded),
// dist bias read from TRANSPOSED fp16 dT[kv][q] (coalesced 64B segments).

typedef __attribute__((ext_vector_type(8))) short bf16x8;
typedef __attribute__((ext_vector_type(4))) float f32x4;
typedef __attribute__((ext_vector_type(16))) float f32x16;
typedef __attribute__((ext_vector_type(4))) unsigned short us4;
typedef __attribute__((ext_vector_type(2))) unsigned int u32x2;
typedef __attribute__((ext_vector_type(8))) _Float16 f16x8;

#define MFMA(a, b, c) __builtin_amdgcn_mfma_f32_16x16x32_bf16((a), (b), (c), 0, 0, 0)
#define MFMA32(a, b, c) __builtin_amdgcn_mfma_f32_32x32x16_bf16((a), (b), (c), 0, 0, 0)

__device__ __forceinline__ unsigned short f2bf(float f) {
  unsigned u = __float_as_uint(f);
  u += 0x7fffu + ((u >> 16) & 1u);       // round-to-nearest-even
  return (unsigned short)(u >> 16);
}

__device__ __forceinline__ unsigned cvtpk_bf16(float lo, float hi) {
  unsigned r;
  asm("v_cvt_pk_bf16_f32 %0, %1, %2" : "=v"(r) : "v"(lo), "v"(hi));
  return r;  // lo in bits[15:0], hi in bits[31:16]
}

// swap upper 32 lanes of a with lower 32 lanes of b
#define PLSWAP(a, b) asm volatile("v_permlane32_swap_b32 %0, %1" : "+v"(a), "+v"(b))

__device__ __forceinline__ float tree16(const float* p) {
  float t0 = (p[0] + p[1]) + (p[2] + p[3]);
  float t1 = (p[4] + p[5]) + (p[6] + p[7]);
  float t2 = (p[8] + p[9]) + (p[10] + p[11]);
  float t3 = (p[12] + p[13]) + (p[14] + p[15]);
  return (t0 + t1) + (t2 + t3);
}

// ---------- elementwise f32 -> bf16, 8 elems/thread ----------
__global__ __launch_bounds__(256) void k_conv(const float* __restrict__ in,
                                              short* __restrict__ out, int n8) {
  int i = blockIdx.x * blockDim.x + threadIdx.x;
  if (i >= n8) return;
  float4 a = ((const float4*)in)[2 * i];
  float4 b = ((const float4*)in)[2 * i + 1];
  us4 lo, hi;
  lo.x = f2bf(a.x); lo.y = f2bf(a.y); lo.z = f2bf(a.z); lo.w = f2bf(a.w);
  hi.x = f2bf(b.x); hi.y = f2bf(b.y); hi.z = f2bf(b.z); hi.w = f2bf(b.w);
  us4* o = (us4*)(out + 8 * (size_t)i);
  o[0] = lo; o[1] = hi;
}

// ---------- tiled transpose + convert: in[R][C] f32 -> out[C][R] bf16 ----------
__global__ void k_transpose(const float* __restrict__ in, short* __restrict__ out,
                            int R, int C) {
  __shared__ float t[32][33];
  int c0 = blockIdx.x * 32, r0 = blockIdx.y * 32;
  int tx = threadIdx.x, ty = threadIdx.y;
#pragma unroll
  for (int j = 0; j < 32; j += 8)
    t[ty + j][tx] = in[(size_t)(r0 + ty + j) * C + c0 + tx];
  __syncthreads();
#pragma unroll
  for (int j = 0; j < 32; j += 8)
    out[(size_t)(c0 + ty + j) * R + r0 + tx] = (short)f2bf(t[tx][ty + j]);
}

// ---------- tiled transpose + convert: in[R][C] f32 -> out[C][R] fp16 ----------
__global__ void k_transpose_h(const float* __restrict__ in, _Float16* __restrict__ out,
                              int R, int C) {
  __shared__ float t[32][33];
  int c0 = blockIdx.x * 32, r0 = blockIdx.y * 32;
  int tx = threadIdx.x, ty = threadIdx.y;
#pragma unroll
  for (int j = 0; j < 32; j += 8)
    t[ty + j][tx] = in[(size_t)(r0 + ty + j) * C + c0 + tx];
  __syncthreads();
#pragma unroll
  for (int j = 0; j < 32; j += 8)
    out[(size_t)(c0 + ty + j) * R + r0 + tx] = (_Float16)t[tx][ty + j];
}

// ---------- GEMM C[M][N] = A[M][K] * (B[N][K])^T, bf16 in, f32 acc ----------
// BM=128: 4 waves in 2x2, each 64x64 of the 128x128 tile.
// BM=64 : 4 waves side-by-side, each 64x32 of the 64x128 tile (occupancy variant).
// MODE 0: scatter qkv into Q (pre-scaled by 2^-5*log2e), K, Vt. MODE 1: f32 C.
template <int MODE, int BM>
__global__ __launch_bounds__(256) void k_gemm(const short* __restrict__ A,
                                              const short* __restrict__ B,
                                              const float* __restrict__ bias,
                                              void* __restrict__ C0, void* __restrict__ C1,
                                              void* __restrict__ C2, int M, int N, int K) {
  __shared__ __align__(16) short bufA[2][BM * 32];
  __shared__ __align__(16) short bufB[2][128 * 32];
  const int tid = threadIdx.x, lane = tid & 63, wave = tid >> 6;
  const int m0 = blockIdx.y * BM, n0 = blockIdx.x * 128;
  const int wm = (BM == 128) ? (wave >> 1) * 64 : 0;
  const int wn = (BM == 128) ? (wave & 1) * 64 : wave * 32;
  const int NI = (BM == 128) ? 4 : 2;
  const int KT = K >> 5;
  f32x4 acc[4][4] = {};

  const short* ga = A + (size_t)m0 * K;
  const short* gb = B + (size_t)n0 * K;

#define STAGE(kt, bsel)                                                                   \
  {                                                                                       \
    const short* pa = ga + (kt) * 32;                                                     \
    const short* pb = gb + (kt) * 32;                                                     \
    _Pragma("unroll") for (int i = 0; i < BM / 64; i++) {                                 \
      int s = i * 256 + tid;                                                              \
      __builtin_amdgcn_global_load_lds(                                                   \
          (const __attribute__((address_space(1))) void*)(pa + (size_t)(s >> 2) * K +     \
                                                          (s & 3) * 8),                   \
          (__attribute__((address_space(3))) void*)(&bufA[bsel][(i * 256 + wave * 64) * 8]), \
          16, 0, 0);                                                                      \
    }                                                                                     \
    _Pragma("unroll") for (int i = 0; i < 2; i++) {                                       \
      int s = i * 256 + tid;                                                              \
      __builtin_amdgcn_global_load_lds(                                                   \
          (const __attribute__((address_space(1))) void*)(pb + (size_t)(s >> 2) * K +     \
                                                          (s & 3) * 8),                   \
          (__attribute__((address_space(3))) void*)(&bufB[bsel][(i * 256 + wave * 64) * 8]), \
          16, 0, 0);                                                                      \
    }                                                                                     \
  }

  STAGE(0, 0)
  for (int kt = 0; kt < KT; ++kt) {
    const int cur = kt & 1;
    __syncthreads();
    if (kt + 1 < KT) STAGE(kt + 1, cur ^ 1)
    bf16x8 af[4], bfr[4];
#pragma unroll
    for (int i = 0; i < 4; i++)
      af[i] = *(const bf16x8*)&bufA[cur][(wm + i * 16 + (lane & 15)) * 32 + (lane >> 4) * 8];
#pragma unroll
    for (int i = 0; i < NI; i++)
      bfr[i] = *(const bf16x8*)&bufB[cur][(wn + i * 16 + (lane & 15)) * 32 + (lane >> 4) * 8];
#pragma unroll
    for (int mi = 0; mi < 4; mi++)
#pragma unroll
      for (int ni = 0; ni < NI; ni++) acc[mi][ni] = MFMA(af[mi], bfr[ni], acc[mi][ni]);
  }
#undef STAGE

#pragma unroll
  for (int mi = 0; mi < 4; mi++)
#pragma unroll
    for (int ni = 0; ni < NI; ni++) {
      int row0 = m0 + wm + mi * 16 + (lane >> 4) * 4;
      int col = n0 + wn + ni * 16 + (lane & 15);
      float bv = bias[col];
      if constexpr (MODE == 0) {
        int which = col >> 10, h = (col >> 6) & 15, d = col & 63;
        int b = row0 >> 11, nt0 = row0 & 2047;
        if (which == 2) {
          us4 pk;
          pk.x = f2bf(acc[mi][ni][0] + bv);
          pk.y = f2bf(acc[mi][ni][1] + bv);
          pk.z = f2bf(acc[mi][ni][2] + bv);
          pk.w = f2bf(acc[mi][ni][3] + bv);
          *(us4*)((short*)C2 + ((size_t)((b << 4) + h) * 64 + d) * 2048 + nt0) = pk;
        } else {
          // Q gets pre-scaled by 2^-5 * log2(e) so attn bias is a single FMA
          float sc = (which == 0) ? 0.045084220f : 1.0f;
          short* dst = (which == 0) ? (short*)C0 : (short*)C1;
#pragma unroll
          for (int r = 0; r < 4; r++)
            dst[((size_t)((b << 4) + h) * 2048 + nt0 + r) * 64 + d] =
                (short)f2bf((acc[mi][ni][r] + bv) * sc);
        }
      } else {
        float* o = (float*)C0;
#pragma unroll
        for (int r = 0; r < 4; r++) o[(size_t)(row0 + r) * N + col] = acc[mi][ni][r] + bv;
      }
    }
}

// ---------- fused attention: 32x32x16 swapped-QK, 2 KV-groups, no-max softmax ----------
// Q[bh][n][64] (pre-scaled), K[bh][n][64], Vt[bh][64][n] bf16; dT[kv][q] fp16; out bf16.
// 512 threads = 8 waves; waves 0-3 (group 0) do even 64-KV tiles, 4-7 odd tiles.
// Lane pair (l, l^32) owns q-row qbase+(l&31). Scores bounded (|x|<~5 in log2
// domain) -> softmax without max tracking; group partials merge by plain add.
// Bias loads: per kv-slot, lanes 0-31 read 32 consecutive q entries of dT ->
// 2x64B fully-used segments per instruction (vs 32-segment row-gather).
__global__ __launch_bounds__(512, 4) void k_attn(const short* __restrict__ Qb,
                                                 const short* __restrict__ Kb,
                                                 const short* __restrict__ Vt,
                                                 const float* __restrict__ gamma,
                                                 const _Float16* __restrict__ dT,
                                                 short* __restrict__ attn_out) {
  __shared__ __align__(16) short bufK[2][2][64 * 64];   // [group][dbuf]
  __shared__ __align__(16) short bufV[2][2][64 * 64];
  __shared__ float mls[4][32];
  const int tid = threadIdx.x;
  const int lane = tid & 63, wave = tid >> 6;
  const int grp = wave >> 2, w4 = wave & 3;
  const int q32 = lane & 31, hl = lane >> 5;
  const int w = blockIdx.x;
  const int xcd = w & 7, idx = w >> 3;
  const int bh = (xcd << 2) | (idx >> 4);        // 4 heads per XCD
  const int qblock = idx & 15;                   // 16 q-blocks of 128 rows
  const int qbase = qblock * 128 + w4 * 32;
  const float G2 = gamma[bh] * 1.4426950408889634f;
  const size_t head = (size_t)bh * 2048 * 64;
  const int qrow = qbase + q32;                  // q-row owned by this lane pair
  const _Float16* dcol = dT + qrow;              // dT[kv][2048], this lane's column
  const char* kptr = (const char*)(Kb + head);   // [2048][64] bf16, 128B rows
  const char* vptr = (const char*)(Vt + head);   // [64][2048] bf16, 4096B rows
  const int swz = (q32 & 7) << 4;

  // Q B-frags (already scaled by 2^-5*log2e): col=q32, k-slice ds*16 + hl*8
  bf16x8 qf[4];
#pragma unroll
  for (int ds = 0; ds < 4; ds++)
    qf[ds] = *(const bf16x8*)&Qb[head + (size_t)qrow * 64 + ds * 16 + hl * 8];

  // Stage this group's 64x64 bf16 K and V tiles (8KB each): 256 group-threads
  // x 2 x 16B. LDS linear; global source pre-applies XOR (byte ^= (row&7)<<4).
#define STAGEKV(kb, bsel)                                                                  \
  {                                                                                        \
    _Pragma("unroll") for (int i = 0; i < 2; i++) {                                        \
      int s = i * 256 + (tid & 255);                                                       \
      int row = s >> 3, sw = ((s & 7) * 16) ^ ((row & 7) << 4);                            \
      __builtin_amdgcn_global_load_lds(                                                    \
          (const __attribute__((address_space(1))) void*)(kptr + (size_t)(kb) * 128 +      \
                                                          row * 128 + sw),                 \
          (__attribute__((address_space(3))) void*)(&bufK[grp][bsel][(i * 256 + w4 * 64) * 8]),\
          16, 0, 0);                                                                       \
      __builtin_amdgcn_global_load_lds(                                                    \
          (const __attribute__((address_space(1))) void*)(vptr + (size_t)row * 4096 +      \
                                                          (size_t)(kb) * 2 + sw),          \
          (__attribute__((address_space(3))) void*)(&bufV[grp][bsel][(i * 256 + w4 * 64) * 8]),\
          16, 0, 0);                                                                       \
    }                                                                                      \
  }

  float ls = 0.f;
  f32x16 acc0 = {}, acc1 = {};

  STAGEKV(grp * 64, 0)

  // dist for this group's first tile: kv slot = kb + t*32 + 8a + 4hl + b
  float dd0[16], dd1[16];
#pragma unroll
  for (int a = 0; a < 4; a++)
#pragma unroll
    for (int b = 0; b < 4; b++) {
      dd0[4 * a + b] = (float)dcol[(size_t)(grp * 64 + 8 * a + 4 * hl + b) * 2048];
      dd1[4 * a + b] = (float)dcol[(size_t)(grp * 64 + 32 + 8 * a + 4 * hl + b) * 2048];
    }

  for (int it = 0; it < 16; ++it) {
    const int cur = it & 1;
    const int kb = (2 * it + grp) * 64;
    __syncthreads();  // staged tiles (both groups) landed; prev LDS reads done
    if (it + 1 < 16) STAGEKV(kb + 128, cur ^ 1)

    // ---- QK^T: A = K rows (kv), B = Q ----
    const char* kbase = (const char*)&bufK[grp][cur][0];
    f32x16 s0 = {}, s1 = {};
#pragma unroll
    for (int ds = 0; ds < 4; ds++) {
      int c = (ds * 32 + hl * 16) ^ swz;
      bf16x8 a0 = *(const bf16x8*)(kbase + q32 * 128 + c);
      bf16x8 a1 = *(const bf16x8*)(kbase + (32 + q32) * 128 + c);
      s0 = MFMA32(a0, qf[ds], s0);
      s1 = MFMA32(a1, qf[ds], s1);
    }

    // ---- no-max softmax: p = exp2(s - G2*d); reg 4a+b -> kv = t*32+8a+4hl+b ----
    float p0[16], p1[16];
#pragma unroll
    for (int r = 0; r < 16; r++) {
      p0[r] = __builtin_amdgcn_exp2f(s0[r] - G2 * dd0[r]);
      p1[r] = __builtin_amdgcn_exp2f(s1[r] - G2 * dd1[r]);
    }
    ls += tree16(p0) + tree16(p1);

    // ---- P -> bf16 B-frags in-register ----
    unsigned P0[4][2], P1[4][2];
#pragma unroll
    for (int a = 0; a < 4; a++)
#pragma unroll
      for (int wd = 0; wd < 2; wd++) {
        P0[a][wd] = cvtpk_bf16(p0[4 * a + 2 * wd], p0[4 * a + 2 * wd + 1]);
        P1[a][wd] = cvtpk_bf16(p1[4 * a + 2 * wd], p1[4 * a + 2 * wd + 1]);
      }
    PLSWAP(P0[0][0], P0[1][0]); PLSWAP(P0[0][1], P0[1][1]);
    PLSWAP(P0[2][0], P0[3][0]); PLSWAP(P0[2][1], P0[3][1]);
    PLSWAP(P1[0][0], P1[1][0]); PLSWAP(P1[0][1], P1[1][1]);
    PLSWAP(P1[2][0], P1[3][0]); PLSWAP(P1[2][1], P1[3][1]);

    union { unsigned u[4]; bf16x8 v; } pf00, pf01, pf10, pf11;
    pf00.u[0] = P0[0][0]; pf00.u[1] = P0[0][1]; pf00.u[2] = P0[1][0]; pf00.u[3] = P0[1][1];
    pf01.u[0] = P0[2][0]; pf01.u[1] = P0[2][1]; pf01.u[2] = P0[3][0]; pf01.u[3] = P0[3][1];
    pf10.u[0] = P1[0][0]; pf10.u[1] = P1[0][1]; pf10.u[2] = P1[1][0]; pf10.u[3] = P1[1][1];
    pf11.u[0] = P1[2][0]; pf11.u[1] = P1[2][1]; pf11.u[2] = P1[3][0]; pf11.u[3] = P1[3][1];

    // ---- PV: A = Vt rows (dv), B = P ----
    const char* vbase = (const char*)&bufV[grp][cur][0];
#pragma unroll
    for (int dt = 0; dt < 2; dt++) {
      f32x16* ac = dt ? &acc1 : &acc0;
      int vr = (dt * 32 + q32) * 128;
      bf16x8 v00 = *(const bf16x8*)(vbase + vr + ((0 * 64 + 0 * 32 + hl * 16) ^ swz));
      bf16x8 v01 = *(const bf16x8*)(vbase + vr + ((0 * 64 + 1 * 32 + hl * 16) ^ swz));
      bf16x8 v10 = *(const bf16x8*)(vbase + vr + ((1 * 64 + 0 * 32 + hl * 16) ^ swz));
      bf16x8 v11 = *(const bf16x8*)(vbase + vr + ((1 * 64 + 1 * 32 + hl * 16) ^ swz));
      *ac = MFMA32(v00, pf00.v, *ac);
      *ac = MFMA32(v01, pf01.v, *ac);
      *ac = MFMA32(v10, pf10.v, *ac);
      *ac = MFMA32(v11, pf11.v, *ac);
    }

    // ---- dist for next own tile (issued at bottom; drained by next barrier) ----
    const int kbn = (kb + 128) & 2047;
#pragma unroll
    for (int a = 0; a < 4; a++)
#pragma unroll
      for (int b = 0; b < 4; b++) {
        dd0[4 * a + b] = (float)dcol[(size_t)(kbn + 8 * a + 4 * hl + b) * 2048];
        dd1[4 * a + b] = (float)dcol[(size_t)(kbn + 32 + 8 * a + 4 * hl + b) * 2048];
      }
  }
#undef STAGEKV

  // ---- merge group partials (plain add: same softmax scale, no max) ----
  __syncthreads();
  float* mrg = (float*)&bufK[0][0][0];  // [4][32][64] f32, 16B-chunk XOR by q32&15
  if (grp == 1) {
    float lsr = ls + __shfl_xor(ls, 32, 64);
    if (hl == 0) mls[w4][q32] = lsr;
#pragma unroll
    for (int dt = 0; dt < 2; dt++) {
      const f32x16* ac = dt ? &acc1 : &acc0;
#pragma unroll
      for (int a = 0; a < 4; a++) {
        int chunk = (dt * 8 + a * 2 + hl) ^ (q32 & 15);
        f32x4 v;
        v.x = (*ac)[4 * a + 0]; v.y = (*ac)[4 * a + 1];
        v.z = (*ac)[4 * a + 2]; v.w = (*ac)[4 * a + 3];
        *(f32x4*)((char*)mrg + (w4 * 32 + q32) * 256 + chunk * 16) = v;
      }
    }
  }
  __syncthreads();
  if (grp == 0) {
    const int b_ = bh >> 4, h_ = bh & 15;
    float lsr = ls + __shfl_xor(ls, 32, 64);
    float linv = 1.0f / (lsr + mls[w4][q32]);
    size_t base = ((size_t)b_ * 2048 + qrow) * 1024 + h_ * 64;
#pragma unroll
    for (int dt = 0; dt < 2; dt++) {
      const f32x16* ac = dt ? &acc1 : &acc0;
#pragma unroll
      for (int a = 0; a < 4; a++) {
        int chunk = (dt * 8 + a * 2 + hl) ^ (q32 & 15);
        f32x4 vB = *(const f32x4*)((const char*)mrg + (w4 * 32 + q32) * 256 + chunk * 16);
        u32x2 wv;
        wv.x = cvtpk_bf16(((*ac)[4 * a + 0] + vB.x) * linv, ((*ac)[4 * a + 1] + vB.y) * linv);
        wv.y = cvtpk_bf16(((*ac)[4 * a + 2] + vB.z) * linv, ((*ac)[4 * a + 3] + vB.w) * linv);
        *(u32x2*)&attn_out[base + dt * 32 + a * 8 + hl * 4] = wv;
      }
    }
  }
}

extern "C" void kernel_launch(void* const* d_in, const int* in_sizes, int n_in,
                              void* d_out, int out_size, void* d_ws, size_t ws_size,
                              hipStream_t stream) {
  const float* x = (const float*)d_in[0];       // [2,2048,1024]
  const float* gamma = (const float*)d_in[1];   // [2,16]
  const float* dist = (const float*)d_in[2];    // [2048,2048]
  const float* qkv_w = (const float*)d_in[3];   // [1024,3072]
  const float* qkv_b = (const float*)d_in[4];   // [3072]
  const float* proj_w = (const float*)d_in[5];  // [1024,1024]
  const float* proj_b = (const float*)d_in[6];  // [1024]
  float* out = (float*)d_out;                   // [4096,1024]

  const size_t MB = 1024 * 1024;
  char* ws = (char*)d_ws;
  short* xb = (short*)(ws + 0 * MB);     // 8MB  x bf16 [4096][1024]
  short* wT = (short*)(ws + 8 * MB);     // 6MB  qkv_w^T bf16 [3072][1024]
  short* pT = (short*)(ws + 14 * MB);    // 2MB  proj_w^T bf16 [1024][1024]
  short* Qb = (short*)(ws + 16 * MB);    // 8MB  [32][2048][64] (pre-scaled)
  short* Kb = (short*)(ws + 24 * MB);    // 8MB
  short* Vt = (short*)(ws + 32 * MB);    // 8MB  [32][64][2048]
  _Float16* dT = (_Float16*)(ws + 40 * MB);  // 8MB dist^T fp16 [kv=2048][q=2048]
  short* attn = (short*)(ws + 0 * MB);   // reuse xb region: [4096][1024] bf16

  // x -> bf16
  k_conv<<<dim3((4096 * 1024 / 8 + 255) / 256), dim3(256), 0, stream>>>(x, xb, 4096 * 1024 / 8);
  // dist -> transposed fp16 dT[kv][q]
  k_transpose_h<<<dim3(64, 64), dim3(32, 8), 0, stream>>>(dist, dT, 2048, 2048);
  // weight transposes
  k_transpose<<<dim3(96, 32), dim3(32, 8), 0, stream>>>(qkv_w, wT, 1024, 3072);
  k_transpose<<<dim3(32, 32), dim3(32, 8), 0, stream>>>(proj_w, pT, 1024, 1024);
  // qkv projection + scatter
  k_gemm<0, 128><<<dim3(24, 32), dim3(256), 0, stream>>>(xb, wT, qkv_b, Qb, Kb, Vt,
                                                         4096, 3072, 1024);
  // attention
  k_attn<<<dim3(512), dim3(512), 0, stream>>>(Qb, Kb, Vt, gamma, dT, attn);
  // output projection (64-row tiles: 512 blocks -> 2 blocks/CU)
  k_gemm<1, 64><<<dim3(8, 64), dim3(256), 0, stream>>>(attn, pT, proj_b, out, nullptr, nullptr,
                                                       4096, 1024, 1024);
}

// Round 10
// 138.059 us; speedup vs baseline: 1.3026x; 1.0706x over previous
//
#include <hip/hip_runtime.h>
#include <hip/hip_bf16.h>

// ZoomAttention: x[2,2048,1024] -> qkv proj -> 16-head attn with -gamma*dist bias -> proj
// GEMMs: C = A * B^T with bf16 MFMA 16x16x32 (XCD-swizzled block order).
// Attention: 32x32x16 swapped-QK flash, 2 KV-groups per block (8 waves), no-max
// softmax (scores provably bounded), dist bias from TRANSPOSED fp16 dT[kv][q]
// (coalesced 64B segments), dist loads at loop BOTTOM (round-7 known-good schedule;
// top placement empirically mis-executes — rounds 8/9).
// Prep (x->bf16, dist->dT fp16, 2 weight transposes) fused into one launch.

typedef __attribute__((ext_vector_type(8))) short bf16x8;
typedef __attribute__((ext_vector_type(4))) float f32x4;
typedef __attribute__((ext_vector_type(16))) float f32x16;
typedef __attribute__((ext_vector_type(4))) unsigned short us4;
typedef __attribute__((ext_vector_type(2))) unsigned int u32x2;

#define MFMA(a, b, c) __builtin_amdgcn_mfma_f32_16x16x32_bf16((a), (b), (c), 0, 0, 0)
#define MFMA32(a, b, c) __builtin_amdgcn_mfma_f32_32x32x16_bf16((a), (b), (c), 0, 0, 0)

__device__ __forceinline__ unsigned short f2bf(float f) {
  unsigned u = __float_as_uint(f);
  u += 0x7fffu + ((u >> 16) & 1u);       // round-to-nearest-even
  return (unsigned short)(u >> 16);
}

__device__ __forceinline__ unsigned cvtpk_bf16(float lo, float hi) {
  unsigned r;
  asm("v_cvt_pk_bf16_f32 %0, %1, %2" : "=v"(r) : "v"(lo), "v"(hi));
  return r;  // lo in bits[15:0], hi in bits[31:16]
}

// swap upper 32 lanes of a with lower 32 lanes of b
#define PLSWAP(a, b) asm volatile("v_permlane32_swap_b32 %0, %1" : "+v"(a), "+v"(b))

__device__ __forceinline__ float tree16(const float* p) {
  float t0 = (p[0] + p[1]) + (p[2] + p[3]);
  float t1 = (p[4] + p[5]) + (p[6] + p[7]);
  float t2 = (p[8] + p[9]) + (p[10] + p[11]);
  float t3 = (p[12] + p[13]) + (p[14] + p[15]);
  return (t0 + t1) + (t2 + t3);
}

// ---------- fused prep: segmented grid, 256 threads/block ----------
// seg A [0,2048):        x f32 -> xb bf16, 8 elems/thread
// seg B [2048,6144):     dist [2048][2048] f32 -> dT [kv][q] fp16 (transpose)
// seg C [6144,9216):     qkv_w [1024][3072] f32 -> wT [3072][1024] bf16 (transpose)
// seg D [9216,10240):    proj_w [1024][1024] f32 -> pT [1024][1024] bf16 (transpose)
__global__ __launch_bounds__(256) void k_prep(const float* __restrict__ x,
                                              short* __restrict__ xb,
                                              const float* __restrict__ dist,
                                              _Float16* __restrict__ dT,
                                              const float* __restrict__ qkv_w,
                                              short* __restrict__ wT,
                                              const float* __restrict__ proj_w,
                                              short* __restrict__ pT) {
  __shared__ float t[32][33];
  const int b = blockIdx.x, tid = threadIdx.x;
  if (b < 2048) {  // ---- seg A: convert x ----
    int i = b * 256 + tid;
    float4 a = ((const float4*)x)[2 * i];
    float4 c = ((const float4*)x)[2 * i + 1];
    us4 lo, hi;
    lo.x = f2bf(a.x); lo.y = f2bf(a.y); lo.z = f2bf(a.z); lo.w = f2bf(a.w);
    hi.x = f2bf(c.x); hi.y = f2bf(c.y); hi.z = f2bf(c.z); hi.w = f2bf(c.w);
    us4* o = (us4*)(xb + 8 * (size_t)i);
    o[0] = lo; o[1] = hi;
    return;
  }
  const int tx = tid & 31, ty = tid >> 5;  // 32x8 layout for transposes
  if (b < 6144) {  // ---- seg B: dist -> dT fp16 ----
    int bb = b - 2048;
    int c0 = (bb & 63) * 32, r0 = (bb >> 6) * 32;  // R=C=2048
#pragma unroll
    for (int j = 0; j < 32; j += 8)
      t[ty + j][tx] = dist[(size_t)(r0 + ty + j) * 2048 + c0 + tx];
    __syncthreads();
#pragma unroll
    for (int j = 0; j < 32; j += 8)
      dT[(size_t)(c0 + ty + j) * 2048 + r0 + tx] = (_Float16)t[tx][ty + j];
    return;
  }
  if (b < 9216) {  // ---- seg C: qkv_w [1024][3072] -> wT [3072][1024] bf16 ----
    int bb = b - 6144;
    int c0 = (bb % 96) * 32, r0 = (bb / 96) * 32;  // R=1024, C=3072
#pragma unroll
    for (int j = 0; j < 32; j += 8)
      t[ty + j][tx] = qkv_w[(size_t)(r0 + ty + j) * 3072 + c0 + tx];
    __syncthreads();
#pragma unroll
    for (int j = 0; j < 32; j += 8)
      wT[(size_t)(c0 + ty + j) * 1024 + r0 + tx] = (short)f2bf(t[tx][ty + j]);
    return;
  }
  {  // ---- seg D: proj_w [1024][1024] -> pT bf16 ----
    int bb = b - 9216;
    int c0 = (bb & 31) * 32, r0 = (bb >> 5) * 32;  // R=C=1024
#pragma unroll
    for (int j = 0; j < 32; j += 8)
      t[ty + j][tx] = proj_w[(size_t)(r0 + ty + j) * 1024 + c0 + tx];
    __syncthreads();
#pragma unroll
    for (int j = 0; j < 32; j += 8)
      pT[(size_t)(c0 + ty + j) * 1024 + r0 + tx] = (short)f2bf(t[tx][ty + j]);
  }
}

// ---------- GEMM C[M][N] = A[M][K] * (B[N][K])^T, bf16 in, f32 acc ----------
// BM=128: 4 waves in 2x2, each 64x64 of the 128x128 tile.
// BM=64 : 4 waves side-by-side, each 64x32 of the 64x128 tile (occupancy variant).
// MODE 0: scatter qkv into Q (pre-scaled by 2^-5*log2e), K, Vt. MODE 1: f32 C.
// Block order XCD-swizzled (grid count % 8 == 0 -> bijective).
template <int MODE, int BM>
__global__ __launch_bounds__(256) void k_gemm(const short* __restrict__ A,
                                              const short* __restrict__ B,
                                              const float* __restrict__ bias,
                                              void* __restrict__ C0, void* __restrict__ C1,
                                              void* __restrict__ C2, int M, int N, int K) {
  __shared__ __align__(16) short bufA[2][BM * 32];
  __shared__ __align__(16) short bufB[2][128 * 32];
  const int tid = threadIdx.x, lane = tid & 63, wave = tid >> 6;
  // XCD-aware block swizzle: contiguous chunk per XCD (bijective: nwg % 8 == 0)
  const int nwg = gridDim.x * gridDim.y;
  const int wlin = blockIdx.y * gridDim.x + blockIdx.x;
  const int cpx = nwg >> 3;
  const int swzb = (wlin & 7) * cpx + (wlin >> 3);
  const int bx = swzb % gridDim.x, by = swzb / gridDim.x;
  const int m0 = by * BM, n0 = bx * 128;
  const int wm = (BM == 128) ? (wave >> 1) * 64 : 0;
  const int wn = (BM == 128) ? (wave & 1) * 64 : wave * 32;
  const int NI = (BM == 128) ? 4 : 2;
  const int KT = K >> 5;
  f32x4 acc[4][4] = {};

  const short* ga = A + (size_t)m0 * K;
  const short* gb = B + (size_t)n0 * K;

#define STAGE(kt, bsel)                                                                   \
  {                                                                                       \
    const short* pa = ga + (kt) * 32;                                                     \
    const short* pb = gb + (kt) * 32;                                                     \
    _Pragma("unroll") for (int i = 0; i < BM / 64; i++) {                                 \
      int s = i * 256 + tid;                                                              \
      __builtin_amdgcn_global_load_lds(                                                   \
          (const __attribute__((address_space(1))) void*)(pa + (size_t)(s >> 2) * K +     \
                                                          (s & 3) * 8),                   \
          (__attribute__((address_space(3))) void*)(&bufA[bsel][(i * 256 + wave * 64) * 8]), \
          16, 0, 0);                                                                      \
    }                                                                                     \
    _Pragma("unroll") for (int i = 0; i < 2; i++) {                                       \
      int s = i * 256 + tid;                                                              \
      __builtin_amdgcn_global_load_lds(                                                   \
          (const __attribute__((address_space(1))) void*)(pb + (size_t)(s >> 2) * K +     \
                                                          (s & 3) * 8),                   \
          (__attribute__((address_space(3))) void*)(&bufB[bsel][(i * 256 + wave * 64) * 8]), \
          16, 0, 0);                                                                      \
    }                                                                                     \
  }

  STAGE(0, 0)
  for (int kt = 0; kt < KT; ++kt) {
    const int cur = kt & 1;
    __syncthreads();
    if (kt + 1 < KT) STAGE(kt + 1, cur ^ 1)
    bf16x8 af[4], bfr[4];
#pragma unroll
    for (int i = 0; i < 4; i++)
      af[i] = *(const bf16x8*)&bufA[cur][(wm + i * 16 + (lane & 15)) * 32 + (lane >> 4) * 8];
#pragma unroll
    for (int i = 0; i < NI; i++)
      bfr[i] = *(const bf16x8*)&bufB[cur][(wn + i * 16 + (lane & 15)) * 32 + (lane >> 4) * 8];
#pragma unroll
    for (int mi = 0; mi < 4; mi++)
#pragma unroll
      for (int ni = 0; ni < NI; ni++) acc[mi][ni] = MFMA(af[mi], bfr[ni], acc[mi][ni]);
  }
#undef STAGE

#pragma unroll
  for (int mi = 0; mi < 4; mi++)
#pragma unroll
    for (int ni = 0; ni < NI; ni++) {
      int row0 = m0 + wm + mi * 16 + (lane >> 4) * 4;
      int col = n0 + wn + ni * 16 + (lane & 15);
      float bv = bias[col];
      if constexpr (MODE == 0) {
        int which = col >> 10, h = (col >> 6) & 15, d = col & 63;
        int b = row0 >> 11, nt0 = row0 & 2047;
        if (which == 2) {
          us4 pk;
          pk.x = f2bf(acc[mi][ni][0] + bv);
          pk.y = f2bf(acc[mi][ni][1] + bv);
          pk.z = f2bf(acc[mi][ni][2] + bv);
          pk.w = f2bf(acc[mi][ni][3] + bv);
          *(us4*)((short*)C2 + ((size_t)((b << 4) + h) * 64 + d) * 2048 + nt0) = pk;
        } else {
          // Q gets pre-scaled by 2^-5 * log2(e) so attn bias is a single FMA
          float sc = (which == 0) ? 0.045084220f : 1.0f;
          short* dst = (which == 0) ? (short*)C0 : (short*)C1;
#pragma unroll
          for (int r = 0; r < 4; r++)
            dst[((size_t)((b << 4) + h) * 2048 + nt0 + r) * 64 + d] =
                (short)f2bf((acc[mi][ni][r] + bv) * sc);
        }
      } else {
        float* o = (float*)C0;
#pragma unroll
        for (int r = 0; r < 4; r++) o[(size_t)(row0 + r) * N + col] = acc[mi][ni][r] + bv;
      }
    }
}

// ---------- fused attention: 32x32x16 swapped-QK, 2 KV-groups, no-max softmax ----------
// Q[bh][n][64] (pre-scaled), K[bh][n][64], Vt[bh][64][n] bf16; dT[kv][q] fp16; out bf16.
// 512 threads = 8 waves; waves 0-3 (group 0) do even 64-KV tiles, 4-7 odd tiles.
// Lane pair (l, l^32) owns q-row qbase+(l&31). Scores bounded (|x|<~5 in log2
// domain) -> softmax without max tracking; group partials merge by plain add.
// Bias loads: per kv-slot, lanes 0-31 read 32 consecutive q entries of dT ->
// 2x64B fully-used segments per instruction. Loads at loop BOTTOM (known-good).
__global__ __launch_bounds__(512, 4) void k_attn(const short* __restrict__ Qb,
                                                 const short* __restrict__ Kb,
                                                 const short* __restrict__ Vt,
                                                 const float* __restrict__ gamma,
                                                 const _Float16* __restrict__ dT,
                                                 short* __restrict__ attn_out) {
  __shared__ __align__(16) short bufK[2][2][64 * 64];   // [group][dbuf]
  __shared__ __align__(16) short bufV[2][2][64 * 64];
  __shared__ float mls[4][32];
  const int tid = threadIdx.x;
  const int lane = tid & 63, wave = tid >> 6;
  const int grp = wave >> 2, w4 = wave & 3;
  const int q32 = lane & 31, hl = lane >> 5;
  const int w = blockIdx.x;
  const int xcd = w & 7, idx = w >> 3;
  const int bh = (xcd << 2) | (idx >> 4);        // 4 heads per XCD
  const int qblock = idx & 15;                   // 16 q-blocks of 128 rows
  const int qbase = qblock * 128 + w4 * 32;
  const float G2 = gamma[bh] * 1.4426950408889634f;
  const size_t head = (size_t)bh * 2048 * 64;
  const int qrow = qbase + q32;                  // q-row owned by this lane pair
  const _Float16* dcol = dT + qrow;              // dT[kv][2048], this lane's column
  const char* kptr = (const char*)(Kb + head);   // [2048][64] bf16, 128B rows
  const char* vptr = (const char*)(Vt + head);   // [64][2048] bf16, 4096B rows
  const int swz = (q32 & 7) << 4;

  // Q B-frags (already scaled by 2^-5*log2e): col=q32, k-slice ds*16 + hl*8
  bf16x8 qf[4];
#pragma unroll
  for (int ds = 0; ds < 4; ds++)
    qf[ds] = *(const bf16x8*)&Qb[head + (size_t)qrow * 64 + ds * 16 + hl * 8];

  // Stage this group's 64x64 bf16 K and V tiles (8KB each): 256 group-threads
  // x 2 x 16B. LDS linear; global source pre-applies XOR (byte ^= (row&7)<<4).
#define STAGEKV(kb, bsel)                                                                  \
  {                                                                                        \
    _Pragma("unroll") for (int i = 0; i < 2; i++) {                                        \
      int s = i * 256 + (tid & 255);                                                       \
      int row = s >> 3, sw = ((s & 7) * 16) ^ ((row & 7) << 4);                            \
      __builtin_amdgcn_global_load_lds(                                                    \
          (const __attribute__((address_space(1))) void*)(kptr + (size_t)(kb) * 128 +      \
                                                          row * 128 + sw),                 \
          (__attribute__((address_space(3))) void*)(&bufK[grp][bsel][(i * 256 + w4 * 64) * 8]),\
          16, 0, 0);                                                                       \
      __builtin_amdgcn_global_load_lds(                                                    \
          (const __attribute__((address_space(1))) void*)(vptr + (size_t)row * 4096 +      \
                                                          (size_t)(kb) * 2 + sw),          \
          (__attribute__((address_space(3))) void*)(&bufV[grp][bsel][(i * 256 + w4 * 64) * 8]),\
          16, 0, 0);                                                                       \
    }                                                                                      \
  }

  float ls = 0.f;
  f32x16 acc0 = {}, acc1 = {};

  STAGEKV(grp * 64, 0)

  // dist for this group's first tile: kv slot = kb + t*32 + 8a + 4hl + b
  float dd0[16], dd1[16];
#pragma unroll
  for (int a = 0; a < 4; a++)
#pragma unroll
    for (int b = 0; b < 4; b++) {
      dd0[4 * a + b] = (float)dcol[(size_t)(grp * 64 + 8 * a + 4 * hl + b) * 2048];
      dd1[4 * a + b] = (float)dcol[(size_t)(grp * 64 + 32 + 8 * a + 4 * hl + b) * 2048];
    }

  for (int it = 0; it < 16; ++it) {
    const int cur = it & 1;
    const int kb = (2 * it + grp) * 64;
    __syncthreads();  // staged tiles (both groups) landed; prev LDS reads done
    if (it + 1 < 16) STAGEKV(kb + 128, cur ^ 1)

    // ---- QK^T: A = K rows (kv), B = Q ----
    const char* kbase = (const char*)&bufK[grp][cur][0];
    f32x16 s0 = {}, s1 = {};
#pragma unroll
    for (int ds = 0; ds < 4; ds++) {
      int c = (ds * 32 + hl * 16) ^ swz;
      bf16x8 a0 = *(const bf16x8*)(kbase + q32 * 128 + c);
      bf16x8 a1 = *(const bf16x8*)(kbase + (32 + q32) * 128 + c);
      s0 = MFMA32(a0, qf[ds], s0);
      s1 = MFMA32(a1, qf[ds], s1);
    }

    // ---- no-max softmax: p = exp2(s - G2*d); reg 4a+b -> kv = t*32+8a+4hl+b ----
    float p0[16], p1[16];
#pragma unroll
    for (int r = 0; r < 16; r++) {
      p0[r] = __builtin_amdgcn_exp2f(s0[r] - G2 * dd0[r]);
      p1[r] = __builtin_amdgcn_exp2f(s1[r] - G2 * dd1[r]);
    }
    ls += tree16(p0) + tree16(p1);

    // ---- P -> bf16 B-frags in-register ----
    unsigned P0[4][2], P1[4][2];
#pragma unroll
    for (int a = 0; a < 4; a++)
#pragma unroll
      for (int wd = 0; wd < 2; wd++) {
        P0[a][wd] = cvtpk_bf16(p0[4 * a + 2 * wd], p0[4 * a + 2 * wd + 1]);
        P1[a][wd] = cvtpk_bf16(p1[4 * a + 2 * wd], p1[4 * a + 2 * wd + 1]);
      }
    PLSWAP(P0[0][0], P0[1][0]); PLSWAP(P0[0][1], P0[1][1]);
    PLSWAP(P0[2][0], P0[3][0]); PLSWAP(P0[2][1], P0[3][1]);
    PLSWAP(P1[0][0], P1[1][0]); PLSWAP(P1[0][1], P1[1][1]);
    PLSWAP(P1[2][0], P1[3][0]); PLSWAP(P1[2][1], P1[3][1]);

    union { unsigned u[4]; bf16x8 v; } pf00, pf01, pf10, pf11;
    pf00.u[0] = P0[0][0]; pf00.u[1] = P0[0][1]; pf00.u[2] = P0[1][0]; pf00.u[3] = P0[1][1];
    pf01.u[0] = P0[2][0]; pf01.u[1] = P0[2][1]; pf01.u[2] = P0[3][0]; pf01.u[3] = P0[3][1];
    pf10.u[0] = P1[0][0]; pf10.u[1] = P1[0][1]; pf10.u[2] = P1[1][0]; pf10.u[3] = P1[1][1];
    pf11.u[0] = P1[2][0]; pf11.u[1] = P1[2][1]; pf11.u[2] = P1[3][0]; pf11.u[3] = P1[3][1];

    // ---- PV: A = Vt rows (dv), B = P ----
    const char* vbase = (const char*)&bufV[grp][cur][0];
#pragma unroll
    for (int dt = 0; dt < 2; dt++) {
      f32x16* ac = dt ? &acc1 : &acc0;
      int vr = (dt * 32 + q32) * 128;
      bf16x8 v00 = *(const bf16x8*)(vbase + vr + ((0 * 64 + 0 * 32 + hl * 16) ^ swz));
      bf16x8 v01 = *(const bf16x8*)(vbase + vr + ((0 * 64 + 1 * 32 + hl * 16) ^ swz));
      bf16x8 v10 = *(const bf16x8*)(vbase + vr + ((1 * 64 + 0 * 32 + hl * 16) ^ swz));
      bf16x8 v11 = *(const bf16x8*)(vbase + vr + ((1 * 64 + 1 * 32 + hl * 16) ^ swz));
      *ac = MFMA32(v00, pf00.v, *ac);
      *ac = MFMA32(v01, pf01.v, *ac);
      *ac = MFMA32(v10, pf10.v, *ac);
      *ac = MFMA32(v11, pf11.v, *ac);
    }

    // ---- dist for next own tile (issued at bottom; drained by next barrier) ----
    const int kbn = (kb + 128) & 2047;
#pragma unroll
    for (int a = 0; a < 4; a++)
#pragma unroll
      for (int b = 0; b < 4; b++) {
        dd0[4 * a + b] = (float)dcol[(size_t)(kbn + 8 * a + 4 * hl + b) * 2048];
        dd1[4 * a + b] = (float)dcol[(size_t)(kbn + 32 + 8 * a + 4 * hl + b) * 2048];
      }
  }
#undef STAGEKV

  // ---- merge group partials (plain add: same softmax scale, no max) ----
  __syncthreads();
  float* mrg = (float*)&bufK[0][0][0];  // [4][32][64] f32, 16B-chunk XOR by q32&15
  if (grp == 1) {
    float lsr = ls + __shfl_xor(ls, 32, 64);
    if (hl == 0) mls[w4][q32] = lsr;
#pragma unroll
    for (int dt = 0; dt < 2; dt++) {
      const f32x16* ac = dt ? &acc1 : &acc0;
#pragma unroll
      for (int a = 0; a < 4; a++) {
        int chunk = (dt * 8 + a * 2 + hl) ^ (q32 & 15);
        f32x4 v;
        v.x = (*ac)[4 * a + 0]; v.y = (*ac)[4 * a + 1];
        v.z = (*ac)[4 * a + 2]; v.w = (*ac)[4 * a + 3];
        *(f32x4*)((char*)mrg + (w4 * 32 + q32) * 256 + chunk * 16) = v;
      }
    }
  }
  __syncthreads();
  if (grp == 0) {
    const int b_ = bh >> 4, h_ = bh & 15;
    float lsr = ls + __shfl_xor(ls, 32, 64);
    float linv = 1.0f / (lsr + mls[w4][q32]);
    size_t base = ((size_t)b_ * 2048 + qrow) * 1024 + h_ * 64;
#pragma unroll
    for (int dt = 0; dt < 2; dt++) {
      const f32x16* ac = dt ? &acc1 : &acc0;
#pragma unroll
      for (int a = 0; a < 4; a++) {
        int chunk = (dt * 8 + a * 2 + hl) ^ (q32 & 15);
        f32x4 vB = *(const f32x4*)((const char*)mrg + (w4 * 32 + q32) * 256 + chunk * 16);
        u32x2 wv;
        wv.x = cvtpk_bf16(((*ac)[4 * a + 0] + vB.x) * linv, ((*ac)[4 * a + 1] + vB.y) * linv);
        wv.y = cvtpk_bf16(((*ac)[4 * a + 2] + vB.z) * linv, ((*ac)[4 * a + 3] + vB.w) * linv);
        *(u32x2*)&attn_out[base + dt * 32 + a * 8 + hl * 4] = wv;
      }
    }
  }
}

extern "C" void kernel_launch(void* const* d_in, const int* in_sizes, int n_in,
                              void* d_out, int out_size, void* d_ws, size_t ws_size,
                              hipStream_t stream) {
  const float* x = (const float*)d_in[0];       // [2,2048,1024]
  const float* gamma = (const float*)d_in[1];   // [2,16]
  const float* dist = (const float*)d_in[2];    // [2048,2048]
  const float* qkv_w = (const float*)d_in[3];   // [1024,3072]
  const float* qkv_b = (const float*)d_in[4];   // [3072]
  const float* proj_w = (const float*)d_in[5];  // [1024,1024]
  const float* proj_b = (const float*)d_in[6];  // [1024]
  float* out = (float*)d_out;                   // [4096,1024]

  const size_t MB = 1024 * 1024;
  char* ws = (char*)d_ws;
  short* xb = (short*)(ws + 0 * MB);     // 8MB  x bf16 [4096][1024]
  short* wT = (short*)(ws + 8 * MB);     // 6MB  qkv_w^T bf16 [3072][1024]
  short* pT = (short*)(ws + 14 * MB);    // 2MB  proj_w^T bf16 [1024][1024]
  short* Qb = (short*)(ws + 16 * MB);    // 8MB  [32][2048][64] (pre-scaled)
  short* Kb = (short*)(ws + 24 * MB);    // 8MB
  short* Vt = (short*)(ws + 32 * MB);    // 8MB  [32][64][2048]
  _Float16* dT = (_Float16*)(ws + 40 * MB);  // 8MB dist^T fp16 [kv=2048][q=2048]
  short* attn = (short*)(ws + 0 * MB);   // reuse xb region: [4096][1024] bf16

  // fused prep: x->bf16, dist->dT, qkv_w->wT, proj_w->pT
  k_prep<<<dim3(10240), dim3(256), 0, stream>>>(x, xb, dist, dT, qkv_w, wT, proj_w, pT);
  // qkv projection + scatter
  k_gemm<0, 128><<<dim3(24, 32), dim3(256), 0, stream>>>(xb, wT, qkv_b, Qb, Kb, Vt,
                                                         4096, 3072, 1024);
  // attention
  k_attn<<<dim3(512), dim3(512), 0, stream>>>(Qb, Kb, Vt, gamma, dT, attn);
  // output projection (64-row tiles: 512 blocks -> 2 blocks/CU)
  k_gemm<1, 64><<<dim3(8, 64), dim3(256), 0, stream>>>(attn, pT, proj_b, out, nullptr, nullptr,
                                                       4096, 1024, 1024);
}

// Round 11
// 119.204 us; speedup vs baseline: 1.5086x; 1.1582x over previous
//
#include <hip/hip_runtime.h>
#include <hip/hip_bf16.h>

// ZoomAttention: x[2,2048,1024] -> qkv proj -> 16-head attn with -gamma*dist bias -> proj
// GEMMs: C = A * B^T with bf16 MFMA 16x16x32 (XCD-swizzled block order).
// Attention: 32x32x16 swapped-QK flash, 2 KV-groups per block (8 waves), no-max
// softmax (scores provably bounded). dist bias: u8 quad-packed transposed
// dTq8[kv/4][q][4], staged per-tile into LDS via global_load_lds ONE ITERATION
// AHEAD (rides the same vmcnt drain as K/V -> no exposed latency), read as
// conflict-free ds_read_b32, single-buffered with lgkmcnt(0)+s_barrier fence.
// Prep (x->bf16, dist->dTq8, 2 weight transposes) fused into one launch.

typedef __attribute__((ext_vector_type(8))) short bf16x8;
typedef __attribute__((ext_vector_type(4))) float f32x4;
typedef __attribute__((ext_vector_type(16))) float f32x16;
typedef __attribute__((ext_vector_type(4))) unsigned short us4;
typedef __attribute__((ext_vector_type(2))) unsigned int u32x2;

#define MFMA(a, b, c) __builtin_amdgcn_mfma_f32_16x16x32_bf16((a), (b), (c), 0, 0, 0)
#define MFMA32(a, b, c) __builtin_amdgcn_mfma_f32_32x32x16_bf16((a), (b), (c), 0, 0, 0)

__device__ __forceinline__ unsigned short f2bf(float f) {
  unsigned u = __float_as_uint(f);
  u += 0x7fffu + ((u >> 16) & 1u);       // round-to-nearest-even
  return (unsigned short)(u >> 16);
}

__device__ __forceinline__ unsigned cvtpk_bf16(float lo, float hi) {
  unsigned r;
  asm("v_cvt_pk_bf16_f32 %0, %1, %2" : "=v"(r) : "v"(lo), "v"(hi));
  return r;  // lo in bits[15:0], hi in bits[31:16]
}

// swap upper 32 lanes of a with lower 32 lanes of b
#define PLSWAP(a, b) asm volatile("v_permlane32_swap_b32 %0, %1" : "+v"(a), "+v"(b))

__device__ __forceinline__ float tree16(const float* p) {
  float t0 = (p[0] + p[1]) + (p[2] + p[3]);
  float t1 = (p[4] + p[5]) + (p[6] + p[7]);
  float t2 = (p[8] + p[9]) + (p[10] + p[11]);
  float t3 = (p[12] + p[13]) + (p[14] + p[15]);
  return (t0 + t1) + (t2 + t3);
}

// ---------- fused prep: segmented grid, 256 threads/block ----------
// seg A [0,2048):        x f32 -> xb bf16, 8 elems/thread
// seg B [2048,6144):     dist [q=2048][kv=2048] f32 -> dTq8 [kv/4][q][4] u8
// seg C [6144,9216):     qkv_w [1024][3072] f32 -> wT [3072][1024] bf16 (transpose)
// seg D [9216,10240):    proj_w [1024][1024] f32 -> pT [1024][1024] bf16 (transpose)
__global__ __launch_bounds__(256) void k_prep(const float* __restrict__ x,
                                              short* __restrict__ xb,
                                              const float* __restrict__ dist,
                                              unsigned char* __restrict__ dTq8,
                                              const float* __restrict__ qkv_w,
                                              short* __restrict__ wT,
                                              const float* __restrict__ proj_w,
                                              short* __restrict__ pT) {
  __shared__ float t[32][33];
  const int b = blockIdx.x, tid = threadIdx.x;
  if (b < 2048) {  // ---- seg A: convert x ----
    int i = b * 256 + tid;
    float4 a = ((const float4*)x)[2 * i];
    float4 c = ((const float4*)x)[2 * i + 1];
    us4 lo, hi;
    lo.x = f2bf(a.x); lo.y = f2bf(a.y); lo.z = f2bf(a.z); lo.w = f2bf(a.w);
    hi.x = f2bf(c.x); hi.y = f2bf(c.y); hi.z = f2bf(c.z); hi.w = f2bf(c.w);
    us4* o = (us4*)(xb + 8 * (size_t)i);
    o[0] = lo; o[1] = hi;
    return;
  }
  const int tx = tid & 31, ty = tid >> 5;  // 32x8 layout for transposes
  if (b < 6144) {  // ---- seg B: dist -> dTq8 u8 quad-packed transpose ----
    int bb = b - 2048;
    int c0 = (bb & 63) * 32, r0 = (bb >> 6) * 32;  // c = kv, r = q
#pragma unroll
    for (int j = 0; j < 32; j += 8)
      t[ty + j][tx] = dist[(size_t)(r0 + ty + j) * 2048 + c0 + tx];
    __syncthreads();
#pragma unroll
    for (int j = 0; j < 32; j += 8) {
      int c = c0 + ty + j, q = r0 + tx;
      int u = (int)(t[tx][ty + j] * 256.0f + 0.5f);
      u = u > 255 ? 255 : u;
      dTq8[(size_t)(c >> 2) * 8192 + (size_t)q * 4 + (c & 3)] = (unsigned char)u;
    }
    return;
  }
  if (b < 9216) {  // ---- seg C: qkv_w [1024][3072] -> wT [3072][1024] bf16 ----
    int bb = b - 6144;
    int c0 = (bb % 96) * 32, r0 = (bb / 96) * 32;  // R=1024, C=3072
#pragma unroll
    for (int j = 0; j < 32; j += 8)
      t[ty + j][tx] = qkv_w[(size_t)(r0 + ty + j) * 3072 + c0 + tx];
    __syncthreads();
#pragma unroll
    for (int j = 0; j < 32; j += 8)
      wT[(size_t)(c0 + ty + j) * 1024 + r0 + tx] = (short)f2bf(t[tx][ty + j]);
    return;
  }
  {  // ---- seg D: proj_w [1024][1024] -> pT bf16 ----
    int bb = b - 9216;
    int c0 = (bb & 31) * 32, r0 = (bb >> 5) * 32;  // R=C=1024
#pragma unroll
    for (int j = 0; j < 32; j += 8)
      t[ty + j][tx] = proj_w[(size_t)(r0 + ty + j) * 1024 + c0 + tx];
    __syncthreads();
#pragma unroll
    for (int j = 0; j < 32; j += 8)
      pT[(size_t)(c0 + ty + j) * 1024 + r0 + tx] = (short)f2bf(t[tx][ty + j]);
  }
}

// ---------- GEMM C[M][N] = A[M][K] * (B[N][K])^T, bf16 in, f32 acc ----------
// BM=128: 4 waves in 2x2, each 64x64 of the 128x128 tile.
// BM=64 : 4 waves side-by-side, each 64x32 of the 64x128 tile (occupancy variant).
// MODE 0: scatter qkv into Q (pre-scaled by 2^-5*log2e), K, Vt. MODE 1: f32 C.
// Block order XCD-swizzled (grid count % 8 == 0 -> bijective).
template <int MODE, int BM>
__global__ __launch_bounds__(256) void k_gemm(const short* __restrict__ A,
                                              const short* __restrict__ B,
                                              const float* __restrict__ bias,
                                              void* __restrict__ C0, void* __restrict__ C1,
                                              void* __restrict__ C2, int M, int N, int K) {
  __shared__ __align__(16) short bufA[2][BM * 32];
  __shared__ __align__(16) short bufB[2][128 * 32];
  const int tid = threadIdx.x, lane = tid & 63, wave = tid >> 6;
  // XCD-aware block swizzle: contiguous chunk per XCD (bijective: nwg % 8 == 0)
  const int nwg = gridDim.x * gridDim.y;
  const int wlin = blockIdx.y * gridDim.x + blockIdx.x;
  const int cpx = nwg >> 3;
  const int swzb = (wlin & 7) * cpx + (wlin >> 3);
  const int bx = swzb % gridDim.x, by = swzb / gridDim.x;
  const int m0 = by * BM, n0 = bx * 128;
  const int wm = (BM == 128) ? (wave >> 1) * 64 : 0;
  const int wn = (BM == 128) ? (wave & 1) * 64 : wave * 32;
  const int NI = (BM == 128) ? 4 : 2;
  const int KT = K >> 5;
  f32x4 acc[4][4] = {};

  const short* ga = A + (size_t)m0 * K;
  const short* gb = B + (size_t)n0 * K;

#define STAGE(kt, bsel)                                                                   \
  {                                                                                       \
    const short* pa = ga + (kt) * 32;                                                     \
    const short* pb = gb + (kt) * 32;                                                     \
    _Pragma("unroll") for (int i = 0; i < BM / 64; i++) {                                 \
      int s = i * 256 + tid;                                                              \
      __builtin_amdgcn_global_load_lds(                                                   \
          (const __attribute__((address_space(1))) void*)(pa + (size_t)(s >> 2) * K +     \
                                                          (s & 3) * 8),                   \
          (__attribute__((address_space(3))) void*)(&bufA[bsel][(i * 256 + wave * 64) * 8]), \
          16, 0, 0);                                                                      \
    }                                                                                     \
    _Pragma("unroll") for (int i = 0; i < 2; i++) {                                       \
      int s = i * 256 + tid;                                                              \
      __builtin_amdgcn_global_load_lds(                                                   \
          (const __attribute__((address_space(1))) void*)(pb + (size_t)(s >> 2) * K +     \
                                                          (s & 3) * 8),                   \
          (__attribute__((address_space(3))) void*)(&bufB[bsel][(i * 256 + wave * 64) * 8]), \
          16, 0, 0);                                                                      \
    }                                                                                     \
  }

  STAGE(0, 0)
  for (int kt = 0; kt < KT; ++kt) {
    const int cur = kt & 1;
    __syncthreads();
    if (kt + 1 < KT) STAGE(kt + 1, cur ^ 1)
    bf16x8 af[4], bfr[4];
#pragma unroll
    for (int i = 0; i < 4; i++)
      af[i] = *(const bf16x8*)&bufA[cur][(wm + i * 16 + (lane & 15)) * 32 + (lane >> 4) * 8];
#pragma unroll
    for (int i = 0; i < NI; i++)
      bfr[i] = *(const bf16x8*)&bufB[cur][(wn + i * 16 + (lane & 15)) * 32 + (lane >> 4) * 8];
#pragma unroll
    for (int mi = 0; mi < 4; mi++)
#pragma unroll
      for (int ni = 0; ni < NI; ni++) acc[mi][ni] = MFMA(af[mi], bfr[ni], acc[mi][ni]);
  }
#undef STAGE

#pragma unroll
  for (int mi = 0; mi < 4; mi++)
#pragma unroll
    for (int ni = 0; ni < NI; ni++) {
      int row0 = m0 + wm + mi * 16 + (lane >> 4) * 4;
      int col = n0 + wn + ni * 16 + (lane & 15);
      float bv = bias[col];
      if constexpr (MODE == 0) {
        int which = col >> 10, h = (col >> 6) & 15, d = col & 63;
        int b = row0 >> 11, nt0 = row0 & 2047;
        if (which == 2) {
          us4 pk;
          pk.x = f2bf(acc[mi][ni][0] + bv);
          pk.y = f2bf(acc[mi][ni][1] + bv);
          pk.z = f2bf(acc[mi][ni][2] + bv);
          pk.w = f2bf(acc[mi][ni][3] + bv);
          *(us4*)((short*)C2 + ((size_t)((b << 4) + h) * 64 + d) * 2048 + nt0) = pk;
        } else {
          // Q gets pre-scaled by 2^-5 * log2(e) so attn bias is a single FMA
          float sc = (which == 0) ? 0.045084220f : 1.0f;
          short* dst = (which == 0) ? (short*)C0 : (short*)C1;
#pragma unroll
          for (int r = 0; r < 4; r++)
            dst[((size_t)((b << 4) + h) * 2048 + nt0 + r) * 64 + d] =
                (short)f2bf((acc[mi][ni][r] + bv) * sc);
        }
      } else {
        float* o = (float*)C0;
#pragma unroll
        for (int r = 0; r < 4; r++) o[(size_t)(row0 + r) * N + col] = acc[mi][ni][r] + bv;
      }
    }
}

// ---------- fused attention: 32x32x16 swapped-QK, 2 KV-groups, no-max softmax ----------
// Q[bh][n][64] (pre-scaled), K[bh][n][64], Vt[bh][64][n] bf16; dTq8[kv/4][q][4] u8.
// 512 threads = 8 waves; waves 0-3 (group 0) do even 64-KV tiles, 4-7 odd tiles.
// Lane pair (l, l^32) owns q-row qbase+(l&31). Scores bounded -> no-max softmax.
// dist tile [16 quads][128 q][4] u8 (8KB/group) staged via global_load_lds one
// iter ahead; read (conflict-free b32) right after the barrier, then
// lgkmcnt(0)+s_barrier fence before overwriting with next tile's DMA.
// LDS total = 32K (K) + 32K (V) + 16K (dist) = 81920 B -> exactly 2 blocks/CU.
__global__ __launch_bounds__(512, 4) void k_attn(const short* __restrict__ Qb,
                                                 const short* __restrict__ Kb,
                                                 const short* __restrict__ Vt,
                                                 const float* __restrict__ gamma,
                                                 const unsigned char* __restrict__ dTq8,
                                                 short* __restrict__ attn_out) {
  __shared__ __align__(16) short bufK[2][2][64 * 64];   // [group][dbuf] 32 KB
  __shared__ __align__(16) short bufV[2][2][64 * 64];   // 32 KB
  __shared__ __align__(16) unsigned char bufD[2][8192]; // [group] dist tile, 16 KB
  const int tid = threadIdx.x;
  const int lane = tid & 63, wave = tid >> 6;
  const int grp = wave >> 2, w4 = wave & 3;
  const int q32 = lane & 31, hl = lane >> 5;
  const int w = blockIdx.x;
  const int xcd = w & 7, idx = w >> 3;
  const int bh = (xcd << 2) | (idx >> 4);        // 4 heads per XCD
  const int qblock = idx & 15;                   // 16 q-blocks of 128 rows
  const int qbase = qblock * 128 + w4 * 32;
  const float G2b = gamma[bh] * 1.4426950408889634f * (1.0f / 256.0f);
  const size_t head = (size_t)bh * 2048 * 64;
  const int qrow = qbase + q32;                  // q-row owned by this lane pair
  const int qloc = w4 * 32 + q32;                // q within the block's 128 cols
  const size_t qb4 = (size_t)qblock * 512;       // byte offset of q-block in dTq8 row
  const char* kptr = (const char*)(Kb + head);   // [2048][64] bf16, 128B rows
  const char* vptr = (const char*)(Vt + head);   // [64][2048] bf16, 4096B rows
  const int swz = (q32 & 7) << 4;

  // Q B-frags (already scaled by 2^-5*log2e): col=q32, k-slice ds*16 + hl*8
  bf16x8 qf[4];
#pragma unroll
  for (int ds = 0; ds < 4; ds++)
    qf[ds] = *(const bf16x8*)&Qb[head + (size_t)qrow * 64 + ds * 16 + hl * 8];

  // Stage this group's 64x64 bf16 K and V tiles (8KB each): 256 group-threads
  // x 2 x 16B. LDS linear; global source pre-applies XOR (byte ^= (row&7)<<4).
#define STAGEKV(kb, bsel)                                                                  \
  {                                                                                        \
    _Pragma("unroll") for (int i = 0; i < 2; i++) {                                        \
      int s = i * 256 + (tid & 255);                                                       \
      int row = s >> 3, sw = ((s & 7) * 16) ^ ((row & 7) << 4);                            \
      __builtin_amdgcn_global_load_lds(                                                    \
          (const __attribute__((address_space(1))) void*)(kptr + (size_t)(kb) * 128 +      \
                                                          row * 128 + sw),                 \
          (__attribute__((address_space(3))) void*)(&bufK[grp][bsel][(i * 256 + w4 * 64) * 8]),\
          16, 0, 0);                                                                       \
      __builtin_amdgcn_global_load_lds(                                                    \
          (const __attribute__((address_space(1))) void*)(vptr + (size_t)row * 4096 +      \
                                                          (size_t)(kb) * 2 + sw),          \
          (__attribute__((address_space(3))) void*)(&bufV[grp][bsel][(i * 256 + w4 * 64) * 8]),\
          16, 0, 0);                                                                       \
    }                                                                                      \
  }

  // Stage this group's dist tile (8KB u8 = [16 quad-rows][512B]): 2 x 16B/thread.
  // Source row (kb>>2)+row of dTq8 [512][2048*4B], q-slice qb4+cb.
#define DISTDMA(kb)                                                                        \
  {                                                                                        \
    _Pragma("unroll") for (int i = 0; i < 2; i++) {                                        \
      int s = i * 256 + (tid & 255);                                                       \
      int o = s * 16;                                                                      \
      int row = o >> 9, cb = o & 511;                                                      \
      __builtin_amdgcn_global_load_lds(                                                    \
          (const __attribute__((address_space(1))) void*)(dTq8 +                           \
              (size_t)(((kb) >> 2) + row) * 8192 + qb4 + cb),                              \
          (__attribute__((address_space(3))) void*)(&bufD[grp][(i * 256 + w4 * 64) * 16]), \
          16, 0, 0);                                                                       \
    }                                                                                      \
  }

  float ls = 0.f;
  f32x16 acc0 = {}, acc1 = {};

  STAGEKV(grp * 64, 0)
  DISTDMA(grp * 64)

  const unsigned* ldsD = (const unsigned*)&bufD[grp][0];  // [16][128] u32 words

  for (int it = 0; it < 16; ++it) {
    const int cur = it & 1;
    const int kb = (2 * it + grp) * 64;
    __syncthreads();  // tile t K/V + dist landed; prev LDS reads done

    // ---- read dist tile t from LDS (conflict-free b32), then fence before
    // the single dist buffer is overwritten by next tile's DMA.
    unsigned dw0[4], dw1[4];
#pragma unroll
    for (int a = 0; a < 4; a++) {
      dw0[a] = ldsD[(2 * a + hl) * 128 + qloc];
      dw1[a] = ldsD[(8 + 2 * a + hl) * 128 + qloc];
    }
    asm volatile("s_waitcnt lgkmcnt(0)\n\ts_barrier" ::: "memory");

    if (it + 1 < 16) {
      STAGEKV(kb + 128, cur ^ 1)
      DISTDMA(kb + 128)
    }

    // ---- QK^T: A = K rows (kv), B = Q ----
    const char* kbase = (const char*)&bufK[grp][cur][0];
    f32x16 s0 = {}, s1 = {};
#pragma unroll
    for (int ds = 0; ds < 4; ds++) {
      int c = (ds * 32 + hl * 16) ^ swz;
      bf16x8 a0 = *(const bf16x8*)(kbase + q32 * 128 + c);
      bf16x8 a1 = *(const bf16x8*)(kbase + (32 + q32) * 128 + c);
      s0 = MFMA32(a0, qf[ds], s0);
      s1 = MFMA32(a1, qf[ds], s1);
    }

    // ---- no-max softmax: p = exp2(s - G2b*u8); reg 4a+b -> kv = t*32+8a+4hl+b ----
    float p0[16], p1[16];
#pragma unroll
    for (int a = 0; a < 4; a++)
#pragma unroll
      for (int b = 0; b < 4; b++) {
        p0[4 * a + b] = __builtin_amdgcn_exp2f(
            s0[4 * a + b] - G2b * (float)((dw0[a] >> (8 * b)) & 255u));
        p1[4 * a + b] = __builtin_amdgcn_exp2f(
            s1[4 * a + b] - G2b * (float)((dw1[a] >> (8 * b)) & 255u));
      }
    ls += tree16(p0) + tree16(p1);

    // ---- P -> bf16 B-frags in-register ----
    unsigned P0[4][2], P1[4][2];
#pragma unroll
    for (int a = 0; a < 4; a++)
#pragma unroll
      for (int wd = 0; wd < 2; wd++) {
        P0[a][wd] = cvtpk_bf16(p0[4 * a + 2 * wd], p0[4 * a + 2 * wd + 1]);
        P1[a][wd] = cvtpk_bf16(p1[4 * a + 2 * wd], p1[4 * a + 2 * wd + 1]);
      }
    PLSWAP(P0[0][0], P0[1][0]); PLSWAP(P0[0][1], P0[1][1]);
    PLSWAP(P0[2][0], P0[3][0]); PLSWAP(P0[2][1], P0[3][1]);
    PLSWAP(P1[0][0], P1[1][0]); PLSWAP(P1[0][1], P1[1][1]);
    PLSWAP(P1[2][0], P1[3][0]); PLSWAP(P1[2][1], P1[3][1]);

    union { unsigned u[4]; bf16x8 v; } pf00, pf01, pf10, pf11;
    pf00.u[0] = P0[0][0]; pf00.u[1] = P0[0][1]; pf00.u[2] = P0[1][0]; pf00.u[3] = P0[1][1];
    pf01.u[0] = P0[2][0]; pf01.u[1] = P0[2][1]; pf01.u[2] = P0[3][0]; pf01.u[3] = P0[3][1];
    pf10.u[0] = P1[0][0]; pf10.u[1] = P1[0][1]; pf10.u[2] = P1[1][0]; pf10.u[3] = P1[1][1];
    pf11.u[0] = P1[2][0]; pf11.u[1] = P1[2][1]; pf11.u[2] = P1[3][0]; pf11.u[3] = P1[3][1];

    // ---- PV: A = Vt rows (dv), B = P ----
    const char* vbase = (const char*)&bufV[grp][cur][0];
#pragma unroll
    for (int dt = 0; dt < 2; dt++) {
      f32x16* ac = dt ? &acc1 : &acc0;
      int vr = (dt * 32 + q32) * 128;
      bf16x8 v00 = *(const bf16x8*)(vbase + vr + ((0 * 64 + 0 * 32 + hl * 16) ^ swz));
      bf16x8 v01 = *(const bf16x8*)(vbase + vr + ((0 * 64 + 1 * 32 + hl * 16) ^ swz));
      bf16x8 v10 = *(const bf16x8*)(vbase + vr + ((1 * 64 + 0 * 32 + hl * 16) ^ swz));
      bf16x8 v11 = *(const bf16x8*)(vbase + vr + ((1 * 64 + 1 * 32 + hl * 16) ^ swz));
      *ac = MFMA32(v00, pf00.v, *ac);
      *ac = MFMA32(v01, pf01.v, *ac);
      *ac = MFMA32(v10, pf10.v, *ac);
      *ac = MFMA32(v11, pf11.v, *ac);
    }
  }
#undef STAGEKV
#undef DISTDMA

  // ---- merge group partials (plain add: same softmax scale, no max) ----
  __syncthreads();
  float* mrg = (float*)&bufK[0][0][0];  // [4][32][64] f32, 16B-chunk XOR by q32&15
  float* mls = (float*)&bufV[0][0][0];  // [4][32] group-1 l sums (bufV free now)
  if (grp == 1) {
    float lsr = ls + __shfl_xor(ls, 32, 64);
    if (hl == 0) mls[w4 * 32 + q32] = lsr;
#pragma unroll
    for (int dt = 0; dt < 2; dt++) {
      const f32x16* ac = dt ? &acc1 : &acc0;
#pragma unroll
      for (int a = 0; a < 4; a++) {
        int chunk = (dt * 8 + a * 2 + hl) ^ (q32 & 15);
        f32x4 v;
        v.x = (*ac)[4 * a + 0]; v.y = (*ac)[4 * a + 1];
        v.z = (*ac)[4 * a + 2]; v.w = (*ac)[4 * a + 3];
        *(f32x4*)((char*)mrg + (w4 * 32 + q32) * 256 + chunk * 16) = v;
      }
    }
  }
  __syncthreads();
  if (grp == 0) {
    const int b_ = bh >> 4, h_ = bh & 15;
    float lsr = ls + __shfl_xor(ls, 32, 64);
    float linv = 1.0f / (lsr + mls[w4 * 32 + q32]);
    size_t base = ((size_t)b_ * 2048 + qrow) * 1024 + h_ * 64;
#pragma unroll
    for (int dt = 0; dt < 2; dt++) {
      const f32x16* ac = dt ? &acc1 : &acc0;
#pragma unroll
      for (int a = 0; a < 4; a++) {
        int chunk = (dt * 8 + a * 2 + hl) ^ (q32 & 15);
        f32x4 vB = *(const f32x4*)((const char*)mrg + (w4 * 32 + q32) * 256 + chunk * 16);
        u32x2 wv;
        wv.x = cvtpk_bf16(((*ac)[4 * a + 0] + vB.x) * linv, ((*ac)[4 * a + 1] + vB.y) * linv);
        wv.y = cvtpk_bf16(((*ac)[4 * a + 2] + vB.z) * linv, ((*ac)[4 * a + 3] + vB.w) * linv);
        *(u32x2*)&attn_out[base + dt * 32 + a * 8 + hl * 4] = wv;
      }
    }
  }
}

extern "C" void kernel_launch(void* const* d_in, const int* in_sizes, int n_in,
                              void* d_out, int out_size, void* d_ws, size_t ws_size,
                              hipStream_t stream) {
  const float* x = (const float*)d_in[0];       // [2,2048,1024]
  const float* gamma = (const float*)d_in[1];   // [2,16]
  const float* dist = (const float*)d_in[2];    // [2048,2048]
  const float* qkv_w = (const float*)d_in[3];   // [1024,3072]
  const float* qkv_b = (const float*)d_in[4];   // [3072]
  const float* proj_w = (const float*)d_in[5];  // [1024,1024]
  const float* proj_b = (const float*)d_in[6];  // [1024]
  float* out = (float*)d_out;                   // [4096,1024]

  const size_t MB = 1024 * 1024;
  char* ws = (char*)d_ws;
  short* xb = (short*)(ws + 0 * MB);     // 8MB  x bf16 [4096][1024]
  short* wT = (short*)(ws + 8 * MB);     // 6MB  qkv_w^T bf16 [3072][1024]
  short* pT = (short*)(ws + 14 * MB);    // 2MB  proj_w^T bf16 [1024][1024]
  short* Qb = (short*)(ws + 16 * MB);    // 8MB  [32][2048][64] (pre-scaled)
  short* Kb = (short*)(ws + 24 * MB);    // 8MB
  short* Vt = (short*)(ws + 32 * MB);    // 8MB  [32][64][2048]
  unsigned char* dTq8 = (unsigned char*)(ws + 40 * MB);  // 4MB dist^T u8 [512][2048][4]
  short* attn = (short*)(ws + 0 * MB);   // reuse xb region: [4096][1024] bf16

  // fused prep: x->bf16, dist->dTq8, qkv_w->wT, proj_w->pT
  k_prep<<<dim3(10240), dim3(256), 0, stream>>>(x, xb, dist, dTq8, qkv_w, wT, proj_w, pT);
  // qkv projection + scatter
  k_gemm<0, 128><<<dim3(24, 32), dim3(256), 0, stream>>>(xb, wT, qkv_b, Qb, Kb, Vt,
                                                         4096, 3072, 1024);
  // attention
  k_attn<<<dim3(512), dim3(512), 0, stream>>>(Qb, Kb, Vt, gamma, dTq8, attn);
  // output projection (64-row tiles: 512 blocks -> 2 blocks/CU)
  k_gemm<1, 64><<<dim3(8, 64), dim3(256), 0, stream>>>(attn, pT, proj_b, out, nullptr, nullptr,
                                                       4096, 1024, 1024);
}